// Round 12
// baseline (157.069 us; speedup 1.0000x reference)
//
#include <hip/hip_runtime.h>
#include <hip/hip_bf16.h>
#include <math.h>

#define HW    16384
#define Bsz   4
#define CIN   32
#define COUT  64
#define RED   16
#define KKN   49
#define GG    4
#define PW    134           // padded width/height (128 + 2*3)
#define NHALO 25152         // 16 planes * 1572 halo pixels
#define NZB   99            // halo-zero blocks
#define NPXB  1024          // k1 pixel blocks (64 px each)

typedef __hip_bfloat16 bf16;
typedef __attribute__((ext_vector_type(8))) short bf16x8;   // 8 bf16 = 4 VGPR
typedef __attribute__((ext_vector_type(4))) float f32x4;

__device__ __forceinline__ float gelu_f(float x) {
    return 0.5f * x * (1.0f + erff(x * 0.70710678118654752f));
}
__device__ __forceinline__ void unpack_bf2(unsigned u, float& lo, float& hi) {
    lo = __uint_as_float(u << 16);
    hi = __uint_as_float(u & 0xffff0000u);
}
__device__ __forceinline__ unsigned pack_bf2(float lo, float hi) {
    unsigned a = __float_as_uint(lo), b = __float_as_uint(hi);
    a += 0x7fff + ((a >> 16) & 1);
    b += 0x7fff + ((b >> 16) & 1);
    return (a >> 16) | (b & 0xffff0000u);
}
__device__ __forceinline__ unsigned short bf16r(float v) {
    unsigned a = __float_as_uint(v);
    a += 0x7fff + ((a >> 16) & 1);
    return (unsigned short)(a >> 16);
}

// ---- workspace layout (bytes) ----  (bf16 x1pad, round-5 format)
#define OFF_RBUF  9437184
#define OFF_PAR   22020096
#define OFF_XBF   22085632          // par region is 64 KB
// par region: float index offsets
#define PSHC_F 16
#define PSMV_F 80
#define PSC1_F 144
#define PSH1_F 208
// par region: byte offset for bf16 table
#define BCAT 12288                  // wcat ushort[64][96]

// K1 (standalone): blocks 0..NPXB-1 do conv1+reduce for 64 px each, building
// all weight fragments inline from raw weights (bit-identical bf16r math).
// Blocks NPXB..NPXB+NZB-1 zero the x1pad halo; last block preps wcat/par for k34.
__global__ __launch_bounds__(256, 4) void k1_all(
    const float* __restrict__ x, const float* __restrict__ w1,
    const float* __restrict__ wr, const float* __restrict__ gr,
    const float* __restrict__ br, const float* __restrict__ mr,
    const float* __restrict__ vr,
    const float* __restrict__ g1, const float* __restrict__ b1,
    const float* __restrict__ m1, const float* __restrict__ v1,
    const float* __restrict__ w2, const float* __restrict__ g2,
    const float* __restrict__ b2, const float* __restrict__ m2,
    const float* __restrict__ v2,
    const float* __restrict__ wm, const float* __restrict__ bmap,
    const float* __restrict__ gm, const float* __restrict__ betam,
    const float* __restrict__ mm, const float* __restrict__ vm,
    char* __restrict__ parb, unsigned* __restrict__ x1pad,
    unsigned short* __restrict__ xbf, float* __restrict__ rbuf)
{
    __shared__ float x1f[4][16][65];
    int bid = blockIdx.x, t = threadIdx.x;

    if (bid >= NPXB) {
        int hb = bid - NPXB;
        if (hb < NZB) {
            // halo-only zero of x1pad (interior overwritten by px blocks)
            unsigned i = (unsigned)hb * 256u + (unsigned)t;
            if (i < NHALO) {
                unsigned plane = i / 1572u;
                unsigned rem = i - plane * 1572u;
                unsigned row, col;
                if (rem < 804u) {
                    unsigned rr = rem / 134u;
                    col = rem - rr * 134u;
                    row = rr < 3u ? rr : rr + 128u;
                } else {
                    unsigned r2 = rem - 804u;
                    unsigned rr = r2 / 6u;
                    unsigned cc = r2 - rr * 6u;
                    row = rr + 3u;
                    col = cc < 3u ? cc : cc + 128u;
                }
                uint4* q = (uint4*)x1pad + ((size_t)(plane * PW + row) * PW + col) * 2;
                q[0] = make_uint4(0u, 0u, 0u, 0u);
                q[1] = make_uint4(0u, 0u, 0u, 0u);
            }
        } else {
            // wcat + par prep (consumed only by k34, which launches after)
            float* parf = (float*)parb;
            unsigned short* wcat = (unsigned short*)(parb + BCAT);
            for (int i = t; i < 64 * 96; i += 256) {
                int o = i / 96, c = i - o * 96;
                float v;
                if (c < 64) {
                    float s2 = g2[o] * rsqrtf(v2[o] + 1e-5f);
                    float sm = gm[o] * rsqrtf(vm[o] + 1e-5f);
                    v = w2[o * COUT + c] * (s2 / sm);
                } else {
                    v = wm[o * CIN + (c - 64)];
                }
                wcat[i] = bf16r(v);
            }
            if (t < 64) {
                float s2 = g2[t] * rsqrtf(v2[t] + 1e-5f);
                float sm = gm[t] * rsqrtf(vm[t] + 1e-5f);
                parf[PSHC_F + t] = (b2[t] - m2[t] * s2) + (betam[t] + (bmap[t] - mm[t]) * sm);
                parf[PSMV_F + t] = sm;
                float s1 = g1[t] * rsqrtf(v1[t] + 1e-5f);
                parf[PSC1_F + t] = s1;
                parf[PSH1_F + t] = b1[t] - m1[t] * s1;
            }
        }
        return;
    }

    // ---- pixel block: conv1 MFMA -> gelu -> x1pad + xbf; reduce MFMA -> rbuf
    int lane = t & 63;
    int wave = t >> 6;
    int m15 = lane & 15, quad = lane >> 4;
    int base_gpx = bid * 64 + wave * 16;            // 64 px per block, 16 per wave
    int b   = base_gpx >> 14;
    int px0 = base_gpx & (HW - 1);

    // A-frag: load 8 channels (quad*8..+7) of px base_gpx+m15 from x, pack bf16
    int gpx = base_gpx + m15;
    int p   = gpx & (HW - 1);
    unsigned apk[4];
#pragma unroll
    for (int d = 0; d < 4; ++d) {
        float lo = x[((size_t)(b * CIN + quad * 8 + 2 * d)) * HW + p];
        float hi = x[((size_t)(b * CIN + quad * 8 + 2 * d + 1)) * HW + p];
        apk[d] = pack_bf2(lo, hi);
    }
    union BU { uint4 q; bf16x8 v; };
    BU au; au.q = make_uint4(apk[0], apk[1], apk[2], apk[3]);
    bf16x8 Af = au.v;
    // persist xbf for k34 (identical values to old k0 build)
    *(uint4*)&xbf[(size_t)gpx * 32 + quad * 8] = au.q;

    // conv1: B-frags built inline from w1 (bf16r identical to old w1b)
    f32x4 acc[4];
#pragma unroll
    for (int nt = 0; nt < 4; ++nt) {
        int o = nt * 16 + m15;
        unsigned bpk[4];
#pragma unroll
        for (int d = 0; d < 4; ++d) {
            float lo = w1[o * CIN + quad * 8 + 2 * d];
            float hi = w1[o * CIN + quad * 8 + 2 * d + 1];
            bpk[d] = pack_bf2(lo, hi);
        }
        BU bu; bu.q = make_uint4(bpk[0], bpk[1], bpk[2], bpk[3]);
        f32x4 z = {0.f, 0.f, 0.f, 0.f};
        acc[nt] = __builtin_amdgcn_mfma_f32_16x16x32_bf16(Af, bu.v, z, 0, 0, 0);
    }
    // gelu + stage to LDS (D: row px=quad*4+reg, col o=nt*16+m15)
#pragma unroll
    for (int nt = 0; nt < 4; ++nt)
#pragma unroll
        for (int reg = 0; reg < 4; ++reg)
            x1f[wave][quad * 4 + reg][nt * 16 + m15] = gelu_f(acc[nt][reg]);

    __syncthreads();

    // x1pad store: lane l -> px=l>>2, group g=l&3 (16 ch contiguous bf16)
    {
        int pxl = lane >> 2, g = lane & 3;
        int pp = px0 + pxl, h = pp >> 7, w = pp & 127;
        unsigned pk[8];
#pragma unroll
        for (int d = 0; d < 8; ++d)
            pk[d] = pack_bf2(x1f[wave][pxl][g * 16 + 2 * d],
                             x1f[wave][pxl][g * 16 + 2 * d + 1]);
        unsigned* xo = x1pad +
            ((size_t)((b * GG + g) * PW + (h + 3)) * PW + (w + 3)) * 8;
        *(uint4*)xo       = make_uint4(pk[0], pk[1], pk[2], pk[3]);
        *(uint4*)(xo + 4) = make_uint4(pk[4], pk[5], pk[6], pk[7]);
    }

    // reduce: A[m=px][k=c] from LDS (bf16 repack), B[k=c][n=j] from wr*sc inline
    float sc  = gr[m15] * rsqrtf(vr[m15] + 1e-5f);
    float rsh = br[m15] - mr[m15] * sc;
    f32x4 racc = {0.f, 0.f, 0.f, 0.f};
#pragma unroll
    for (int kt = 0; kt < 2; ++kt) {
        bf16x8 A2, B2;
#pragma unroll
        for (int j = 0; j < 8; ++j) {
            A2[j] = (short)bf16r(x1f[wave][m15][kt * 32 + quad * 8 + j]);
            B2[j] = (short)bf16r(wr[m15 * 64 + kt * 32 + quad * 8 + j] * sc);
        }
        racc = __builtin_amdgcn_mfma_f32_16x16x32_bf16(A2, B2, racc, 0, 0, 0);
    }
    // D: row px=quad*4+reg, col j=m15. relu + shift, store rbuf [px][j16]
#pragma unroll
    for (int reg = 0; reg < 4; ++reg) {
        int gp = base_gpx + quad * 4 + reg;
        rbuf[(size_t)gp * 16 + m15] = fmaxf(racc[reg] + rsh, 0.f);
    }
}

// Tap compute macro. s-dot is 4 INDEPENDENT FMA chains (s0..s3, each 4-5 deep)
// then (s0+s1)+(s2+s3): critical path ~26cy vs 64cy for the 16-deep serial
// chain (R11 showed issue-count cuts are neutral -> the chain was the bound).
// f32 reorder perturbs absmax by O(1e-7) against 0.046875 -> passes.
// Accumulates unchanged from R9 (scalar, R11's asm pk_fma reverted).
#define TAPC(kk, TA, TB)                                                  \
    {                                                                     \
        const float* wk = wrow + (kk) * RED;                              \
        float s0 = brow[(kk)];                                            \
        float s1 = rA.y * wk[1];                                          \
        float s2 = rA.z * wk[2];                                          \
        float s3 = rA.w * wk[3];                                          \
        s0 += rA.x * wk[0];                                               \
        s0 += rB.x * wk[4];  s1 += rB.y * wk[5];                          \
        s2 += rB.z * wk[6];  s3 += rB.w * wk[7];                          \
        s0 += rC.x * wk[8];  s1 += rC.y * wk[9];                          \
        s2 += rC.z * wk[10]; s3 += rC.w * wk[11];                         \
        s0 += rD.x * wk[12]; s1 += rD.y * wk[13];                         \
        s2 += rD.z * wk[14]; s3 += rD.w * wk[15];                         \
        float s = (s0 + s1) + (s2 + s3);                                  \
        float lo, hi;                                                     \
        unpack_bf2((TA).x, lo, hi); acc[0] += s*lo; acc[1] += s*hi;       \
        unpack_bf2((TA).y, lo, hi); acc[2] += s*lo; acc[3] += s*hi;       \
        unpack_bf2((TA).z, lo, hi); acc[4] += s*lo; acc[5] += s*hi;       \
        unpack_bf2((TA).w, lo, hi); acc[6] += s*lo; acc[7] += s*hi;       \
        unpack_bf2((TB).x, lo, hi); acc[8] += s*lo; acc[9] += s*hi;       \
        unpack_bf2((TB).y, lo, hi); acc[10]+= s*lo; acc[11]+= s*hi;       \
        unpack_bf2((TB).z, lo, hi); acc[12]+= s*lo; acc[13]+= s*hi;       \
        unpack_bf2((TB).w, lo, hi); acc[14]+= s*lo; acc[15]+= s*hi;       \
    }

// K34: fused involution (phase 1) + conv2/skip MFMA (phase 2).
// Block = 64 px x 4 groups (256 threads), grid = 1024 -> 16 waves/CU.
// Phase 1: R9's depth-2 software pipeline in 8 NAMED uint4s (proven 153.3);
// only change vs R9 is the 4-chain s-dot in TAPC (chain-latency fix).
// R10/R7/R4 lesson stands: no arrays, stage depth <= 2, VGPR cap 128.
__global__ __launch_bounds__(256, 4) void k34_fused(
    const unsigned* __restrict__ x1pad, const float* __restrict__ rbuf,
    const float* __restrict__ wsp, const float* __restrict__ bsp,
    const char* __restrict__ parb, const unsigned short* __restrict__ xbf,
    float* __restrict__ out)
{
    __shared__ unsigned short x2t[64][88];

    const float* par = (const float*)parb;
    int t = threadIdx.x;
    int b = blockIdx.x >> 8;
    int pxblk = (blockIdx.x & 255) << 6;            // 64 px per block (half row)

    // ---- phase 1: involution, 64 px x 4 groups ----
    {
        int pxl = t & 63;
        int g = __builtin_amdgcn_readfirstlane(t >> 6);   // wave-uniform
        int p = pxblk + pxl;
        int h = p >> 7, w0 = p & 127;
        int bg = b * GG + g;

        const float4* rp = (const float4*)&rbuf[((size_t)b * HW + p) * 16];
        float4 rA = rp[0], rB = rp[1], rC = rp[2], rD = rp[3];

        const float* wrow = wsp + g * KKN * RED;
        const float* brow = bsp + g * KKN;
        const unsigned* tp = x1pad + ((size_t)(bg * PW + h) * PW + w0) * 8;

        float acc[RED];
#pragma unroll
        for (int c = 0; c < RED; ++c) acc[c] = 0.f;

        // depth-2 pipeline: taps k,k+1 in cA0/cB0/cA1/cB1; k+2,k+3 loading.
        const unsigned* pn = tp + 8;                     // tap 1 (j=1)
        uint4 cA0 = *(const uint4*)tp, cB0 = *(const uint4*)(tp + 4);
        uint4 cA1 = *(const uint4*)pn, cB1 = *(const uint4*)(pn + 4);
        int jj = 1;                                      // j of tap at pn
#pragma unroll 1
        for (int k = 0; k < KKN - 1; k += 2) {
            const unsigned* q0 = pn + (jj == 6 ? (PW - 6) * 8 : 8);
            int j0 = (jj == 6) ? 0 : jj + 1;
            const unsigned* q1 = q0 + (j0 == 6 ? (PW - 6) * 8 : 8);
            jj = (j0 == 6) ? 0 : j0 + 1;
            uint4 nA0 = *(const uint4*)q0, nB0 = *(const uint4*)(q0 + 4);
            uint4 nA1 = *(const uint4*)q1, nB1 = *(const uint4*)(q1 + 4);
            TAPC(k,     cA0, cB0);
            TAPC(k + 1, cA1, cB1);
            pn = q1;
            cA0 = nA0; cB0 = nB0; cA1 = nA1; cB1 = nB1;
        }
        TAPC(KKN - 1, cA0, cB0);

        unsigned pk[8];
#pragma unroll
        for (int d = 0; d < 8; ++d) {
            int ch0 = g * RED + 2 * d, ch1 = ch0 + 1;
            float v0 = gelu_f(par[PSC1_F + ch0] * acc[2 * d]     + par[PSH1_F + ch0]);
            float v1 = gelu_f(par[PSC1_F + ch1] * acc[2 * d + 1] + par[PSH1_F + ch1]);
            pk[d] = pack_bf2(v0, v1);
        }
        unsigned* xo = (unsigned*)&x2t[pxl][g * RED];
        *(uint4*)xo       = make_uint4(pk[0], pk[1], pk[2], pk[3]);
        *(uint4*)(xo + 4) = make_uint4(pk[4], pk[5], pk[6], pk[7]);
    }

    __syncthreads();

    // ---- phase 2: out = gelu(sm*([x2|x].wcat) + shc), wave = 16 px ----
    {
        int lane = t & 63, wave = t >> 6;
        int m15  = lane & 15;
        int quad = lane >> 4;
        int pxl0 = wave * 16;
        int px0  = pxblk + pxl0;

        const unsigned short* wcat = (const unsigned short*)(parb + BCAT);

        bf16x8 Bf[3][4];
#pragma unroll
        for (int kt = 0; kt < 3; ++kt)
#pragma unroll
            for (int nt = 0; nt < 4; ++nt)
                Bf[kt][nt] = *(const bf16x8*)&wcat[(nt * 16 + m15) * 96 + kt * 32 + quad * 8];

        bf16x8 Af[3];
        Af[0] = *(const bf16x8*)&x2t[pxl0 + m15][quad * 8];
        Af[1] = *(const bf16x8*)&x2t[pxl0 + m15][32 + quad * 8];
        Af[2] = *(const bf16x8*)&xbf[((size_t)(b * HW + px0 + m15)) * 32 + quad * 8];

        f32x4 acc[4];
#pragma unroll
        for (int nt = 0; nt < 4; ++nt) acc[nt] = (f32x4){0.f, 0.f, 0.f, 0.f};
#pragma unroll
        for (int kt = 0; kt < 3; ++kt)
#pragma unroll
            for (int nt = 0; nt < 4; ++nt)
                acc[nt] = __builtin_amdgcn_mfma_f32_16x16x32_bf16(
                    Af[kt], Bf[kt][nt], acc[nt], 0, 0, 0);

#pragma unroll
        for (int nt = 0; nt < 4; ++nt) {
            int o = nt * 16 + m15;
            float smv = par[PSMV_F + o], sh = par[PSHC_F + o];
            float* op = out + (size_t)(b * COUT + o) * HW + px0 + quad * 4;
#pragma unroll
            for (int reg = 0; reg < 4; ++reg)
                op[reg] = gelu_f(smv * acc[nt][reg] + sh);
        }
    }
}

extern "C" void kernel_launch(void* const* d_in, const int* in_sizes, int n_in,
                              void* d_out, int out_size, void* d_ws, size_t ws_size,
                              hipStream_t stream) {
    const float* x    = (const float*)d_in[0];
    const float* w1   = (const float*)d_in[1];
    const float* wr   = (const float*)d_in[2];
    const float* gr   = (const float*)d_in[3];
    const float* br   = (const float*)d_in[4];
    const float* mr   = (const float*)d_in[5];
    const float* vr   = (const float*)d_in[6];
    const float* wsp  = (const float*)d_in[7];
    const float* bsp  = (const float*)d_in[8];
    const float* g1   = (const float*)d_in[9];
    const float* b1   = (const float*)d_in[10];
    const float* m1   = (const float*)d_in[11];
    const float* v1   = (const float*)d_in[12];
    const float* w2   = (const float*)d_in[13];
    const float* g2   = (const float*)d_in[14];
    const float* b2   = (const float*)d_in[15];
    const float* m2   = (const float*)d_in[16];
    const float* v2   = (const float*)d_in[17];
    const float* wm   = (const float*)d_in[18];
    const float* bmap = (const float*)d_in[19];
    const float* gm   = (const float*)d_in[20];
    const float* betam= (const float*)d_in[21];
    const float* mm   = (const float*)d_in[22];
    const float* vm   = (const float*)d_in[23];

    unsigned*       x1pad = (unsigned*)d_ws;
    float*          rbuf  = (float*)((char*)d_ws + OFF_RBUF);
    char*           parb  = (char*)d_ws + OFF_PAR;
    unsigned short* xbf   = (unsigned short*)((char*)d_ws + OFF_XBF);

    k1_all<<<NPXB + NZB + 1, 256, 0, stream>>>(
        x, w1, wr, gr, br, mr, vr, g1, b1, m1, v1,
        w2, g2, b2, m2, v2, wm, bmap, gm, betam, mm, vm,
        parb, x1pad, xbf, rbuf);
    k34_fused<<<Bsz * GG * HW / 256, 256, 0, stream>>>(
        x1pad, rbuf, wsp, bsp, parb, xbf, (float*)d_out);
}

// Round 13
// 153.231 us; speedup vs baseline: 1.0250x; 1.0250x over previous
//
#include <hip/hip_runtime.h>
#include <hip/hip_bf16.h>
#include <math.h>

#define HW    16384
#define Bsz   4
#define CIN   32
#define COUT  64
#define RED   16
#define KKN   49
#define GG    4
#define PW    134           // padded width/height (128 + 2*3)
#define NHALO 25152         // 16 planes * 1572 halo pixels
#define NZB   99            // halo-zero blocks
#define NPXB  1024          // k1 pixel blocks (64 px each)

typedef __hip_bfloat16 bf16;
typedef __attribute__((ext_vector_type(8))) short bf16x8;   // 8 bf16 = 4 VGPR
typedef __attribute__((ext_vector_type(4))) float f32x4;

__device__ __forceinline__ float gelu_f(float x) {
    return 0.5f * x * (1.0f + erff(x * 0.70710678118654752f));
}
__device__ __forceinline__ void unpack_bf2(unsigned u, float& lo, float& hi) {
    lo = __uint_as_float(u << 16);
    hi = __uint_as_float(u & 0xffff0000u);
}
__device__ __forceinline__ unsigned pack_bf2(float lo, float hi) {
    unsigned a = __float_as_uint(lo), b = __float_as_uint(hi);
    a += 0x7fff + ((a >> 16) & 1);
    b += 0x7fff + ((b >> 16) & 1);
    return (a >> 16) | (b & 0xffff0000u);
}
__device__ __forceinline__ unsigned short bf16r(float v) {
    unsigned a = __float_as_uint(v);
    a += 0x7fff + ((a >> 16) & 1);
    return (unsigned short)(a >> 16);
}

// ---- workspace layout (bytes) ----  (bf16 x1pad, round-5 format)
#define OFF_RBUF  9437184
#define OFF_PAR   22020096
#define OFF_XBF   22085632          // par region is 64 KB
// par region: float index offsets
#define PSHC_F 16
#define PSMV_F 80
#define PSC1_F 144
#define PSH1_F 208
// par region: byte offset for bf16 table
#define BCAT 12288                  // wcat ushort[64][96]

// K1 (standalone): blocks 0..NPXB-1 do conv1+reduce for 64 px each, building
// all weight fragments inline from raw weights (bit-identical bf16r math).
// Blocks NPXB..NPXB+NZB-1 zero the x1pad halo; last block preps wcat/par for k34.
__global__ __launch_bounds__(256, 4) void k1_all(
    const float* __restrict__ x, const float* __restrict__ w1,
    const float* __restrict__ wr, const float* __restrict__ gr,
    const float* __restrict__ br, const float* __restrict__ mr,
    const float* __restrict__ vr,
    const float* __restrict__ g1, const float* __restrict__ b1,
    const float* __restrict__ m1, const float* __restrict__ v1,
    const float* __restrict__ w2, const float* __restrict__ g2,
    const float* __restrict__ b2, const float* __restrict__ m2,
    const float* __restrict__ v2,
    const float* __restrict__ wm, const float* __restrict__ bmap,
    const float* __restrict__ gm, const float* __restrict__ betam,
    const float* __restrict__ mm, const float* __restrict__ vm,
    char* __restrict__ parb, unsigned* __restrict__ x1pad,
    unsigned short* __restrict__ xbf, float* __restrict__ rbuf)
{
    __shared__ float x1f[4][16][65];
    int bid = blockIdx.x, t = threadIdx.x;

    if (bid >= NPXB) {
        int hb = bid - NPXB;
        if (hb < NZB) {
            // halo-only zero of x1pad (interior overwritten by px blocks)
            unsigned i = (unsigned)hb * 256u + (unsigned)t;
            if (i < NHALO) {
                unsigned plane = i / 1572u;
                unsigned rem = i - plane * 1572u;
                unsigned row, col;
                if (rem < 804u) {
                    unsigned rr = rem / 134u;
                    col = rem - rr * 134u;
                    row = rr < 3u ? rr : rr + 128u;
                } else {
                    unsigned r2 = rem - 804u;
                    unsigned rr = r2 / 6u;
                    unsigned cc = r2 - rr * 6u;
                    row = rr + 3u;
                    col = cc < 3u ? cc : cc + 128u;
                }
                uint4* q = (uint4*)x1pad + ((size_t)(plane * PW + row) * PW + col) * 2;
                q[0] = make_uint4(0u, 0u, 0u, 0u);
                q[1] = make_uint4(0u, 0u, 0u, 0u);
            }
        } else {
            // wcat + par prep (consumed only by k34, which launches after)
            float* parf = (float*)parb;
            unsigned short* wcat = (unsigned short*)(parb + BCAT);
            for (int i = t; i < 64 * 96; i += 256) {
                int o = i / 96, c = i - o * 96;
                float v;
                if (c < 64) {
                    float s2 = g2[o] * rsqrtf(v2[o] + 1e-5f);
                    float sm = gm[o] * rsqrtf(vm[o] + 1e-5f);
                    v = w2[o * COUT + c] * (s2 / sm);
                } else {
                    v = wm[o * CIN + (c - 64)];
                }
                wcat[i] = bf16r(v);
            }
            if (t < 64) {
                float s2 = g2[t] * rsqrtf(v2[t] + 1e-5f);
                float sm = gm[t] * rsqrtf(vm[t] + 1e-5f);
                parf[PSHC_F + t] = (b2[t] - m2[t] * s2) + (betam[t] + (bmap[t] - mm[t]) * sm);
                parf[PSMV_F + t] = sm;
                float s1 = g1[t] * rsqrtf(v1[t] + 1e-5f);
                parf[PSC1_F + t] = s1;
                parf[PSH1_F + t] = b1[t] - m1[t] * s1;
            }
        }
        return;
    }

    // ---- pixel block: conv1 MFMA -> gelu -> x1pad + xbf; reduce MFMA -> rbuf
    int lane = t & 63;
    int wave = t >> 6;
    int m15 = lane & 15, quad = lane >> 4;
    int base_gpx = bid * 64 + wave * 16;            // 64 px per block, 16 per wave
    int b   = base_gpx >> 14;
    int px0 = base_gpx & (HW - 1);

    // A-frag: load 8 channels (quad*8..+7) of px base_gpx+m15 from x, pack bf16
    int gpx = base_gpx + m15;
    int p   = gpx & (HW - 1);
    unsigned apk[4];
#pragma unroll
    for (int d = 0; d < 4; ++d) {
        float lo = x[((size_t)(b * CIN + quad * 8 + 2 * d)) * HW + p];
        float hi = x[((size_t)(b * CIN + quad * 8 + 2 * d + 1)) * HW + p];
        apk[d] = pack_bf2(lo, hi);
    }
    union BU { uint4 q; bf16x8 v; };
    BU au; au.q = make_uint4(apk[0], apk[1], apk[2], apk[3]);
    bf16x8 Af = au.v;
    // persist xbf for k34 (identical values to old k0 build)
    *(uint4*)&xbf[(size_t)gpx * 32 + quad * 8] = au.q;

    // conv1: B-frags built inline from w1 (bf16r identical to old w1b)
    f32x4 acc[4];
#pragma unroll
    for (int nt = 0; nt < 4; ++nt) {
        int o = nt * 16 + m15;
        unsigned bpk[4];
#pragma unroll
        for (int d = 0; d < 4; ++d) {
            float lo = w1[o * CIN + quad * 8 + 2 * d];
            float hi = w1[o * CIN + quad * 8 + 2 * d + 1];
            bpk[d] = pack_bf2(lo, hi);
        }
        BU bu; bu.q = make_uint4(bpk[0], bpk[1], bpk[2], bpk[3]);
        f32x4 z = {0.f, 0.f, 0.f, 0.f};
        acc[nt] = __builtin_amdgcn_mfma_f32_16x16x32_bf16(Af, bu.v, z, 0, 0, 0);
    }
    // gelu + stage to LDS (D: row px=quad*4+reg, col o=nt*16+m15)
#pragma unroll
    for (int nt = 0; nt < 4; ++nt)
#pragma unroll
        for (int reg = 0; reg < 4; ++reg)
            x1f[wave][quad * 4 + reg][nt * 16 + m15] = gelu_f(acc[nt][reg]);

    __syncthreads();

    // x1pad store: lane l -> px=l>>2, group g=l&3 (16 ch contiguous bf16)
    {
        int pxl = lane >> 2, g = lane & 3;
        int pp = px0 + pxl, h = pp >> 7, w = pp & 127;
        unsigned pk[8];
#pragma unroll
        for (int d = 0; d < 8; ++d)
            pk[d] = pack_bf2(x1f[wave][pxl][g * 16 + 2 * d],
                             x1f[wave][pxl][g * 16 + 2 * d + 1]);
        unsigned* xo = x1pad +
            ((size_t)((b * GG + g) * PW + (h + 3)) * PW + (w + 3)) * 8;
        *(uint4*)xo       = make_uint4(pk[0], pk[1], pk[2], pk[3]);
        *(uint4*)(xo + 4) = make_uint4(pk[4], pk[5], pk[6], pk[7]);
    }

    // reduce: A[m=px][k=c] from LDS (bf16 repack), B[k=c][n=j] from wr*sc inline
    float sc  = gr[m15] * rsqrtf(vr[m15] + 1e-5f);
    float rsh = br[m15] - mr[m15] * sc;
    f32x4 racc = {0.f, 0.f, 0.f, 0.f};
#pragma unroll
    for (int kt = 0; kt < 2; ++kt) {
        bf16x8 A2, B2;
#pragma unroll
        for (int j = 0; j < 8; ++j) {
            A2[j] = (short)bf16r(x1f[wave][m15][kt * 32 + quad * 8 + j]);
            B2[j] = (short)bf16r(wr[m15 * 64 + kt * 32 + quad * 8 + j] * sc);
        }
        racc = __builtin_amdgcn_mfma_f32_16x16x32_bf16(A2, B2, racc, 0, 0, 0);
    }
    // D: row px=quad*4+reg, col j=m15. relu + shift, store rbuf [px][j16]
#pragma unroll
    for (int reg = 0; reg < 4; ++reg) {
        int gp = base_gpx + quad * 4 + reg;
        rbuf[(size_t)gp * 16 + m15] = fmaxf(racc[reg] + rsh, 0.f);
    }
}

// Tap compute macro: s = brow[k] + r.wk; acc += s * unpacked(TA,TB).
// Op order identical to round 5 (bit-exact). [R11 pk_fma and R12 4-chain
// variants both regressed ~3.5us -> phase 1 is latency-bound, not VALU-bound;
// this plain form gives the compiler the best schedule.]
#define TAPC(kk, TA, TB)                                                  \
    {                                                                     \
        const float* wk = wrow + (kk) * RED;                              \
        float s = brow[(kk)];                                             \
        s += rA.x * wk[0];  s += rA.y * wk[1];                            \
        s += rA.z * wk[2];  s += rA.w * wk[3];                            \
        s += rB.x * wk[4];  s += rB.y * wk[5];                            \
        s += rB.z * wk[6];  s += rB.w * wk[7];                            \
        s += rC.x * wk[8];  s += rC.y * wk[9];                            \
        s += rC.z * wk[10]; s += rC.w * wk[11];                           \
        s += rD.x * wk[12]; s += rD.y * wk[13];                           \
        s += rD.z * wk[14]; s += rD.w * wk[15];                           \
        float lo, hi;                                                     \
        unpack_bf2((TA).x, lo, hi); acc[0] += s*lo; acc[1] += s*hi;       \
        unpack_bf2((TA).y, lo, hi); acc[2] += s*lo; acc[3] += s*hi;       \
        unpack_bf2((TA).z, lo, hi); acc[4] += s*lo; acc[5] += s*hi;       \
        unpack_bf2((TA).w, lo, hi); acc[6] += s*lo; acc[7] += s*hi;       \
        unpack_bf2((TB).x, lo, hi); acc[8] += s*lo; acc[9] += s*hi;       \
        unpack_bf2((TB).y, lo, hi); acc[10]+= s*lo; acc[11]+= s*hi;       \
        unpack_bf2((TB).z, lo, hi); acc[12]+= s*lo; acc[13]+= s*hi;       \
        unpack_bf2((TB).w, lo, hi); acc[14]+= s*lo; acc[15]+= s*hi;       \
    }

// K34: fused involution (phase 1) + conv2/skip MFMA (phase 2).
// Block = 64 px x 4 groups (256 threads), grid = 1024 -> 16 waves/CU.
// Phase 1: flat 49-tap loop unrolled by 2 with a DEPTH-2 software pipeline in
// 8 NAMED uint4s (no arrays; rule #20). Taps k+2,k+3 load while taps k,k+1
// compute -> ~220cy compute in flight vs ~200cy L2 latency -> matched.
// PROVEN OPTIMUM (153.3us): R4/R7 full-unroll spills, R8 whole-window LDS
// halves occupancy, R10 row-stream spills, R11/R12 VALU micro-opts regress.
// Final prefetch (tap 49) reads ~3KB past x1pad: still inside workspace,
// read-only, value unused. Tap order k=0..48 -> bit-identical to round 5.
__global__ __launch_bounds__(256, 4) void k34_fused(
    const unsigned* __restrict__ x1pad, const float* __restrict__ rbuf,
    const float* __restrict__ wsp, const float* __restrict__ bsp,
    const char* __restrict__ parb, const unsigned short* __restrict__ xbf,
    float* __restrict__ out)
{
    __shared__ unsigned short x2t[64][88];

    const float* par = (const float*)parb;
    int t = threadIdx.x;
    int b = blockIdx.x >> 8;
    int pxblk = (blockIdx.x & 255) << 6;            // 64 px per block (half row)

    // ---- phase 1: involution, 64 px x 4 groups ----
    {
        int pxl = t & 63;
        int g = __builtin_amdgcn_readfirstlane(t >> 6);   // wave-uniform
        int p = pxblk + pxl;
        int h = p >> 7, w0 = p & 127;
        int bg = b * GG + g;

        const float4* rp = (const float4*)&rbuf[((size_t)b * HW + p) * 16];
        float4 rA = rp[0], rB = rp[1], rC = rp[2], rD = rp[3];

        const float* wrow = wsp + g * KKN * RED;
        const float* brow = bsp + g * KKN;
        const unsigned* tp = x1pad + ((size_t)(bg * PW + h) * PW + w0) * 8;

        float acc[RED];
#pragma unroll
        for (int c = 0; c < RED; ++c) acc[c] = 0.f;

        // depth-2 pipeline: taps k,k+1 in cA0/cB0/cA1/cB1; k+2,k+3 loading.
        const unsigned* pn = tp + 8;                     // tap 1 (j=1)
        uint4 cA0 = *(const uint4*)tp, cB0 = *(const uint4*)(tp + 4);
        uint4 cA1 = *(const uint4*)pn, cB1 = *(const uint4*)(pn + 4);
        int jj = 1;                                      // j of tap at pn
#pragma unroll 1
        for (int k = 0; k < KKN - 1; k += 2) {
            const unsigned* q0 = pn + (jj == 6 ? (PW - 6) * 8 : 8);
            int j0 = (jj == 6) ? 0 : jj + 1;
            const unsigned* q1 = q0 + (j0 == 6 ? (PW - 6) * 8 : 8);
            jj = (j0 == 6) ? 0 : j0 + 1;
            uint4 nA0 = *(const uint4*)q0, nB0 = *(const uint4*)(q0 + 4);
            uint4 nA1 = *(const uint4*)q1, nB1 = *(const uint4*)(q1 + 4);
            TAPC(k,     cA0, cB0);
            TAPC(k + 1, cA1, cB1);
            pn = q1;
            cA0 = nA0; cB0 = nB0; cA1 = nA1; cB1 = nB1;
        }
        TAPC(KKN - 1, cA0, cB0);

        unsigned pk[8];
#pragma unroll
        for (int d = 0; d < 8; ++d) {
            int ch0 = g * RED + 2 * d, ch1 = ch0 + 1;
            float v0 = gelu_f(par[PSC1_F + ch0] * acc[2 * d]     + par[PSH1_F + ch0]);
            float v1 = gelu_f(par[PSC1_F + ch1] * acc[2 * d + 1] + par[PSH1_F + ch1]);
            pk[d] = pack_bf2(v0, v1);
        }
        unsigned* xo = (unsigned*)&x2t[pxl][g * RED];
        *(uint4*)xo       = make_uint4(pk[0], pk[1], pk[2], pk[3]);
        *(uint4*)(xo + 4) = make_uint4(pk[4], pk[5], pk[6], pk[7]);
    }

    __syncthreads();

    // ---- phase 2: out = gelu(sm*([x2|x].wcat) + shc), wave = 16 px ----
    {
        int lane = t & 63, wave = t >> 6;
        int m15  = lane & 15;
        int quad = lane >> 4;
        int pxl0 = wave * 16;
        int px0  = pxblk + pxl0;

        const unsigned short* wcat = (const unsigned short*)(parb + BCAT);

        bf16x8 Bf[3][4];
#pragma unroll
        for (int kt = 0; kt < 3; ++kt)
#pragma unroll
            for (int nt = 0; nt < 4; ++nt)
                Bf[kt][nt] = *(const bf16x8*)&wcat[(nt * 16 + m15) * 96 + kt * 32 + quad * 8];

        bf16x8 Af[3];
        Af[0] = *(const bf16x8*)&x2t[pxl0 + m15][quad * 8];
        Af[1] = *(const bf16x8*)&x2t[pxl0 + m15][32 + quad * 8];
        Af[2] = *(const bf16x8*)&xbf[((size_t)(b * HW + px0 + m15)) * 32 + quad * 8];

        f32x4 acc[4];
#pragma unroll
        for (int nt = 0; nt < 4; ++nt) acc[nt] = (f32x4){0.f, 0.f, 0.f, 0.f};
#pragma unroll
        for (int kt = 0; kt < 3; ++kt)
#pragma unroll
            for (int nt = 0; nt < 4; ++nt)
                acc[nt] = __builtin_amdgcn_mfma_f32_16x16x32_bf16(
                    Af[kt], Bf[kt][nt], acc[nt], 0, 0, 0);

#pragma unroll
        for (int nt = 0; nt < 4; ++nt) {
            int o = nt * 16 + m15;
            float smv = par[PSMV_F + o], sh = par[PSHC_F + o];
            float* op = out + (size_t)(b * COUT + o) * HW + px0 + quad * 4;
#pragma unroll
            for (int reg = 0; reg < 4; ++reg)
                op[reg] = gelu_f(smv * acc[nt][reg] + sh);
        }
    }
}

extern "C" void kernel_launch(void* const* d_in, const int* in_sizes, int n_in,
                              void* d_out, int out_size, void* d_ws, size_t ws_size,
                              hipStream_t stream) {
    const float* x    = (const float*)d_in[0];
    const float* w1   = (const float*)d_in[1];
    const float* wr   = (const float*)d_in[2];
    const float* gr   = (const float*)d_in[3];
    const float* br   = (const float*)d_in[4];
    const float* mr   = (const float*)d_in[5];
    const float* vr   = (const float*)d_in[6];
    const float* wsp  = (const float*)d_in[7];
    const float* bsp  = (const float*)d_in[8];
    const float* g1   = (const float*)d_in[9];
    const float* b1   = (const float*)d_in[10];
    const float* m1   = (const float*)d_in[11];
    const float* v1   = (const float*)d_in[12];
    const float* w2   = (const float*)d_in[13];
    const float* g2   = (const float*)d_in[14];
    const float* b2   = (const float*)d_in[15];
    const float* m2   = (const float*)d_in[16];
    const float* v2   = (const float*)d_in[17];
    const float* wm   = (const float*)d_in[18];
    const float* bmap = (const float*)d_in[19];
    const float* gm   = (const float*)d_in[20];
    const float* betam= (const float*)d_in[21];
    const float* mm   = (const float*)d_in[22];
    const float* vm   = (const float*)d_in[23];

    unsigned*       x1pad = (unsigned*)d_ws;
    float*          rbuf  = (float*)((char*)d_ws + OFF_RBUF);
    char*           parb  = (char*)d_ws + OFF_PAR;
    unsigned short* xbf   = (unsigned short*)((char*)d_ws + OFF_XBF);

    k1_all<<<NPXB + NZB + 1, 256, 0, stream>>>(
        x, w1, wr, gr, br, mr, vr, g1, b1, m1, v1,
        w2, g2, b2, m2, v2, wm, bmap, gm, betam, mm, vm,
        parb, x1pad, xbf, rbuf);
    k34_fused<<<Bsz * GG * HW / 256, 256, 0, stream>>>(
        x1pad, rbuf, wsp, bsp, parb, xbf, (float*)d_out);
}